// Round 2
// baseline (361.011 us; speedup 1.0000x reference)
//
#include <hip/hip_runtime.h>
#include <math.h>

#define H_HEADS 33
#define C_CH    16
#define HC      528      // H_HEADS * C_CH
#define JG      11       // head groups of 3 (48 cols each)
#define F_IN    128
#define NEG_SLOPE 0.2f

typedef short  bf16x8  __attribute__((ext_vector_type(8)));
typedef float  floatx4 __attribute__((ext_vector_type(4)));

__device__ inline unsigned short f2bf(float f) {   // RNE float->bf16
    unsigned int u = __float_as_uint(f);
    unsigned int r = u + 0x7fffu + ((u >> 16) & 1u);
    return (unsigned short)(r >> 16);
}
__device__ inline float bf2f(unsigned short u) {
    return __uint_as_float((unsigned int)u << 16);
}

// ---------------------------------------------------------------------------
// K0: Wt = bf16(W^T), [528][128].
// ---------------------------------------------------------------------------
__global__ void cvt_w_kernel(const float* __restrict__ W,
                             unsigned short* __restrict__ Wt)
{
    int g = blockIdx.x * blockDim.x + threadIdx.x;
    if (g >= F_IN * HC) return;
    int k = g / HC, n = g % HC;
    Wt[n * F_IN + k] = f2bf(W[g]);
}

// ---------------------------------------------------------------------------
// K1: h = x @ W via MFMA 16x16x32 bf16. One block per 64 rows; f32 x-tile
// staged once (bf16 convert fused), A fragments in registers, 11 head-groups
// looped internally (Wt is L2-resident).
// Output layout is COLUMN-BLOCKED: hb[j][row][48] — each block's store
// region per j is one contiguous, fully-covered 6KB span (32B-aligned 32B
// stores), killing the 4.2x write amplification seen with row-major [N][528].
// a_src/a_dst accumulate in LDS [64][33] and dump once, coalesced.
// ---------------------------------------------------------------------------
#define LDA 136
__global__ __launch_bounds__(256) void gemm_att_kernel(
    const float* __restrict__ x, const unsigned short* __restrict__ Wt,
    const float* __restrict__ att_src, const float* __restrict__ att_dst,
    unsigned short* __restrict__ hb,
    float* __restrict__ a_src, float* __restrict__ a_dst, int N)
{
    __shared__ unsigned short As[64][LDA];   // As[m][k]
    __shared__ unsigned short Bs[48][LDA];   // Bs[n][k] (= Wt rows)
    __shared__ float aS[64][H_HEADS];
    __shared__ float aD[64][H_HEADS];

    const int tid  = threadIdx.x;
    const int lane = tid & 63;
    const int wave = tid >> 6;
    const int lm   = lane & 15;
    const int kc   = lane >> 4;
    const int m0   = blockIdx.x * 64;
    const size_t segN = (size_t)N * 48;

    // stage As from f32 x, converting: 64 rows x 32 float4 chunks
    for (int e = tid; e < 64 * 32; e += 256) {
        int r = e >> 5, c = e & 31;
        int gr = m0 + r;
        float4 v = (gr < N) ? ((const float4*)(x + (size_t)gr * F_IN))[c]
                            : make_float4(0.f, 0.f, 0.f, 0.f);
        unsigned int lo = (unsigned int)f2bf(v.x) | ((unsigned int)f2bf(v.y) << 16);
        unsigned int hi = (unsigned int)f2bf(v.z) | ((unsigned int)f2bf(v.w) << 16);
        *(uint2*)&As[r][c * 4] = make_uint2(lo, hi);
    }
    __syncthreads();

    // A fragments live in registers across all 11 head-group iterations
    const int arow = wave * 16 + lm;
    bf16x8 afrag[4];
    #pragma unroll
    for (int ks = 0; ks < 4; ++ks)
        afrag[ks] = *(const bf16x8*)&As[arow][ks * 32 + kc * 8];

    #pragma unroll 1
    for (int j = 0; j < JG; ++j) {
        __syncthreads();   // previous iteration's Bs reads done
        for (int e = tid; e < 48 * 16; e += 256) {
            int r = e >> 4, c = e & 15;
            uint4 v = ((const uint4*)(Wt + (size_t)(j * 48 + r) * F_IN))[c];
            *(uint4*)&Bs[r][c * 8] = v;
        }
        __syncthreads();

        floatx4 acc[3] = {};
        #pragma unroll
        for (int ks = 0; ks < 4; ++ks) {
            #pragma unroll
            for (int t = 0; t < 3; ++t) {
                bf16x8 b = *(const bf16x8*)&Bs[t * 16 + lm][ks * 32 + kc * 8];
                acc[t] = __builtin_amdgcn_mfma_f32_16x16x32_bf16(afrag[ks], b, acc[t], 0, 0, 0);
            }
        }

        // C/D layout: col = lane&15, row = (lane>>4)*4 + reg
        #pragma unroll
        for (int t = 0; t < 3; ++t) {
            const int head = j * 3 + t;
            const float w_s = att_src[head * C_CH + lm];
            const float w_d = att_dst[head * C_CH + lm];
            #pragma unroll
            for (int rr = 0; rr < 4; ++rr) {
                const int rl  = wave * 16 + kc * 4 + rr;
                const int row = m0 + rl;
                float s = acc[t][rr] * w_s;
                float d = acc[t][rr] * w_d;
                #pragma unroll
                for (int m = 8; m >= 1; m >>= 1) {   // reduce across the 16 lm lanes
                    s += __shfl_xor(s, m);
                    d += __shfl_xor(d, m);
                }
                if (row < N) {
                    hb[(size_t)j * segN + (size_t)row * 48 + t * 16 + lm] = f2bf(acc[t][rr]);
                    if (lm == 0) { aS[rl][head] = s; aD[rl][head] = d; }
                }
            }
        }
    }

    // coalesced dump of a_src/a_dst (LDS flat [64][33] == global row-major)
    __syncthreads();
    const int rows = (N - m0 < 64) ? (N - m0) : 64;
    for (int e = tid; e < rows * H_HEADS; e += 256) {
        a_src[(size_t)m0 * H_HEADS + e] = ((const float*)aS)[e];
        a_dst[(size_t)m0 * H_HEADS + e] = ((const float*)aD)[e];
    }
}

// ---------------------------------------------------------------------------
// Counting sort of edges (incl. self loops) by src (for aggregate's h gather
// locality) AND by dst (for atomic-free denom). One histogram pass builds
// both histograms; one scatter pass builds both orderings.
// ---------------------------------------------------------------------------
__global__ void hist_kernel(const int* __restrict__ ei,
                            int* __restrict__ hist_s, int* __restrict__ hist_d,
                            int E, int Et)
{
    int g = blockIdx.x * blockDim.x + threadIdx.x;
    if (g >= Et) return;
    int src, dst;
    if (g < E) { src = ei[g]; dst = ei[E + g]; }
    else       { src = dst = g - E; }
    atomicAdd(&hist_s[src], 1);
    atomicAdd(&hist_d[dst], 1);
}

// exclusive scan of hist[n] -> o0[n] and o1[n], single block, 8 elems/thread
__global__ __launch_bounds__(1024) void scan_kernel(const int* __restrict__ hist,
                                                    int* __restrict__ o0,
                                                    int* __restrict__ o1, int n)
{
    __shared__ int warp_sums[16];
    __shared__ int s_carry;
    const int tid  = threadIdx.x;
    const int lane = tid & 63, wid = tid >> 6;
    if (tid == 0) s_carry = 0;
    __syncthreads();
    const int n8 = (n + 7) >> 3;
    for (int base = 0; base < n8; base += 1024) {
        int i8 = base + tid;
        int v[8];
        if (i8 * 8 + 8 <= n) {
            *(int4*)&v[0] = ((const int4*)hist)[i8 * 2];
            *(int4*)&v[4] = ((const int4*)hist)[i8 * 2 + 1];
        } else {
            #pragma unroll
            for (int k = 0; k < 8; ++k) v[k] = (i8 * 8 + k < n) ? hist[i8 * 8 + k] : 0;
        }
        int tsum = 0;
        #pragma unroll
        for (int k = 0; k < 8; ++k) tsum += v[k];
        int s = tsum;
        #pragma unroll
        for (int dd = 1; dd < 64; dd <<= 1) {
            int t = __shfl_up(s, dd);
            if (lane >= dd) s += t;
        }
        if (lane == 63) warp_sums[wid] = s;
        __syncthreads();
        if (tid < 16) {
            int ws = warp_sums[tid];
            #pragma unroll
            for (int dd = 1; dd < 16; dd <<= 1) {
                int t = __shfl_up(ws, dd);
                if (tid >= dd) ws += t;
            }
            warp_sums[tid] = ws;
        }
        __syncthreads();
        int excl = s_carry + (wid ? warp_sums[wid - 1] : 0) + (s - tsum);
        int o[8];
        #pragma unroll
        for (int k = 0; k < 8; ++k) { o[k] = excl; excl += v[k]; }
        if (i8 * 8 + 8 <= n) {
            ((int4*)o0)[i8 * 2] = *(int4*)&o[0]; ((int4*)o0)[i8 * 2 + 1] = *(int4*)&o[4];
            ((int4*)o1)[i8 * 2] = *(int4*)&o[0]; ((int4*)o1)[i8 * 2 + 1] = *(int4*)&o[4];
        } else {
            for (int k = 0; k < 8; ++k)
                if (i8 * 8 + k < n) { o0[i8 * 8 + k] = o[k]; o1[i8 * 8 + k] = o[k]; }
        }
        __syncthreads();
        if (tid == 0) s_carry = s_carry + warp_sums[15];
        __syncthreads();
    }
}

__global__ void scatter_kernel(const int* __restrict__ ei,
                               int* __restrict__ cur_s, int* __restrict__ cur_d,
                               int* __restrict__ es, int* __restrict__ ed,
                               int* __restrict__ ss2, int E, int Et)
{
    int g = blockIdx.x * blockDim.x + threadIdx.x;
    if (g >= Et) return;
    int src, dst;
    if (g < E) { src = ei[g]; dst = ei[E + g]; }
    else       { src = dst = g - E; }
    int ps = atomicAdd(&cur_s[src], 1);
    es[ps] = src;
    ed[ps] = dst;
    int pd = atomicAdd(&cur_d[dst], 1);
    ss2[pd] = src;
}

// ---------------------------------------------------------------------------
// K2: denom, atomic-free. One wave per destination node: its incoming edges
// are a contiguous run in the dst-sorted ss2 array. Lanes 0..32 = heads.
// Software-pipelined ss2 load to cut the dependent-load chain.
// ---------------------------------------------------------------------------
__global__ __launch_bounds__(256) void denom_kernel(
    const int* __restrict__ off_d, const int* __restrict__ ss2,
    const float* __restrict__ a_src, const float* __restrict__ a_dst,
    float* __restrict__ denom, int N, int Et)
{
    const int d = blockIdx.x * 4 + (threadIdx.x >> 6);
    if (d >= N) return;
    const int lane = threadIdx.x & 63;
    const int beg = off_d[d];
    const int end = (d + 1 < N) ? off_d[d + 1] : Et;
    const float ad = (lane < H_HEADS) ? a_dst[d * H_HEADS + lane] : 0.f;
    float acc = 0.f;
    int src = ss2[beg];
    for (int e = beg; e < end; ++e) {
        int nxt = (e + 1 < end) ? ss2[e + 1] : 0;
        float v = (lane < H_HEADS) ? (a_src[src * H_HEADS + lane] + ad) : 0.f;
        v = v > 0.f ? v : NEG_SLOPE * v;
        acc += __expf(v);
        src = nxt;
    }
    if (lane < H_HEADS) denom[d * H_HEADS + lane] = acc;
}

// ---------------------------------------------------------------------------
// K3: 64 src-sorted edges/block. Phase 1: 64x33 alphas into LDS (inv folded).
// Phase 2: lane (edge,c) gathers bf16 h from the 11 column-block segments
// (same src repeats across consecutive edges -> cache hits), one atomic per
// (edge,c). Bijective XCD-chunk swizzle keeps a src run on one XCD's L2.
// ---------------------------------------------------------------------------
#define EPB 64
__global__ __launch_bounds__(256) void aggregate_kernel(
    const int* __restrict__ es, const int* __restrict__ ed,
    const float* __restrict__ a_src, const float* __restrict__ a_dst,
    const float* __restrict__ denom,
    const unsigned short* __restrict__ hb,
    float* __restrict__ out, int N, int Et)
{
    __shared__ int   s_src[EPB], s_dst[EPB];
    __shared__ float s_alpha[EPB][H_HEADS];

    // bijective XCD-chunked block swizzle (m204 formula)
    const int nwg = gridDim.x;
    const int q = nwg >> 3, r = nwg & 7;
    const int xcd = blockIdx.x & 7, idx = blockIdx.x >> 3;
    const int bid = (xcd < r ? xcd * (q + 1) : r * (q + 1) + (xcd - r) * q) + idx;

    const int tid = threadIdx.x;
    const int e0  = bid * EPB;
    const size_t segN = (size_t)N * 48;

    if (tid < EPB * 2) {
        int el = tid & (EPB - 1);
        int e  = e0 + el;
        int v  = 0;
        if (e < Et) v = (tid < EPB) ? es[e] : ed[e];
        if (tid < EPB) s_src[el] = v; else s_dst[el] = v;
    }
    __syncthreads();

    for (int i = tid; i < EPB * H_HEADS; i += 256) {
        int el = i / H_HEADS, hd = i - el * H_HEADS;
        if (e0 + el < Et) {
            int src = s_src[el], dst = s_dst[el];
            float v = a_src[src * H_HEADS + hd] + a_dst[dst * H_HEADS + hd];
            v = v > 0.f ? v : NEG_SLOPE * v;
            s_alpha[el][hd] = __expf(v) / (denom[dst * H_HEADS + hd] + 1e-16f);
        }
    }
    __syncthreads();

    const int elq = tid >> 4, c = tid & 15;
    for (int el = elq; el < EPB; el += 16) {
        int e = e0 + el;
        if (e >= Et) break;
        int src = s_src[el], dst = s_dst[el];
        const unsigned short* hp = hb + (size_t)src * 48 + c;
        float acc = 0.f;
        #pragma unroll
        for (int j = 0; j < JG; ++j) {
            const unsigned short* pj = hp + (size_t)j * segN;
            acc += s_alpha[el][j * 3 + 0] * bf2f(pj[0]);
            acc += s_alpha[el][j * 3 + 1] * bf2f(pj[16]);
            acc += s_alpha[el][j * 3 + 2] * bf2f(pj[32]);
        }
        atomicAdd(&out[dst * C_CH + c], acc);
    }
}

// K4: out = tanh(out/H + bias), in place
__global__ void finalize_kernel(float* __restrict__ out,
                                const float* __restrict__ bias, int total)
{
    int g = blockIdx.x * blockDim.x + threadIdx.x;
    if (g >= total) return;
    out[g] = tanhf(out[g] * (1.0f / 33.0f) + bias[g & 15]);
}

// ---------------------------------------------------------------------------
extern "C" void kernel_launch(void* const* d_in, const int* in_sizes, int n_in,
                              void* d_out, int out_size, void* d_ws, size_t ws_size,
                              hipStream_t stream)
{
    const float* x       = (const float*)d_in[0];
    const int*   ei      = (const int*)  d_in[1];
    const float* W       = (const float*)d_in[2];
    const float* att_src = (const float*)d_in[3];
    const float* att_dst = (const float*)d_in[4];
    const float* bias    = (const float*)d_in[5];
    float* out = (float*)d_out;

    const int N  = in_sizes[0] / F_IN;   // 50000
    const int E  = in_sizes[1] / 2;      // 320000
    const int Et = E + N;                // with self loops

    // workspace layout (all 16B-aligned for these sizes)
    unsigned short* hb = (unsigned short*)d_ws;          // 11 * N * 48 bf16
    float* a_src  = (float*)(hb + (size_t)N * HC);
    float* a_dst  = a_src + (size_t)N * H_HEADS;
    float* denom  = a_dst + (size_t)N * H_HEADS;
    int*   es     = (int*)(denom + (size_t)N * H_HEADS);
    int*   ed     = es + Et;
    int*   ss2    = ed + Et;
    int*   hist_s = ss2 + Et;
    int*   hist_d = hist_s + N;
    int*   cur_s  = hist_d + N;
    int*   cur_d  = cur_s + N;
    int*   off_d  = cur_d + N;
    unsigned short* Wt = (unsigned short*)(off_d + N);

    hipMemsetAsync(d_out, 0, (size_t)out_size * sizeof(float), stream);
    hipMemsetAsync(hist_s, 0, 2 * (size_t)N * sizeof(int), stream);  // hist_s + hist_d

    cvt_w_kernel<<<(F_IN * HC + 255) / 256, 256, 0, stream>>>(W, Wt);

    gemm_att_kernel<<<(N + 63) / 64, 256, 0, stream>>>(x, Wt, att_src, att_dst,
                                                       hb, a_src, a_dst, N);

    hist_kernel<<<(Et + 255) / 256, 256, 0, stream>>>(ei, hist_s, hist_d, E, Et);
    scan_kernel<<<1, 1024, 0, stream>>>(hist_s, cur_s, cur_s, N);
    scan_kernel<<<1, 1024, 0, stream>>>(hist_d, cur_d, off_d, N);
    scatter_kernel<<<(Et + 255) / 256, 256, 0, stream>>>(ei, cur_s, cur_d,
                                                         es, ed, ss2, E, Et);

    denom_kernel<<<(N + 3) / 4, 256, 0, stream>>>(off_d, ss2, a_src, a_dst,
                                                  denom, N, Et);

    aggregate_kernel<<<(Et + EPB - 1) / EPB, 256, 0, stream>>>(
        es, ed, a_src, a_dst, denom, hb, out, N, Et);

    int totO = N * C_CH;
    finalize_kernel<<<(totO + 255) / 256, 256, 0, stream>>>(out, bias, totO);
}

// Round 3
// 273.460 us; speedup vs baseline: 1.3202x; 1.3202x over previous
//
#include <hip/hip_runtime.h>
#include <math.h>

#define H_HEADS 33
#define C_CH    16
#define HC      528      // H_HEADS * C_CH
#define JG      11       // head groups of 3 (48 cols each) for h
#define JGT     13       // + 2 groups: att_src logits, att_dst logits
#define F_IN    128
#define NEG_SLOPE 0.2f

typedef short  bf16x8  __attribute__((ext_vector_type(8)));
typedef float  floatx4 __attribute__((ext_vector_type(4)));

__device__ inline unsigned short f2bf(float f) {   // RNE float->bf16
    unsigned int u = __float_as_uint(f);
    unsigned int r = u + 0x7fffu + ((u >> 16) & 1u);
    return (unsigned short)(r >> 16);
}
__device__ inline float bf2f(unsigned short u) {
    return __uint_as_float((unsigned int)u << 16);
}

// ---------------------------------------------------------------------------
// K0a: Wt[0..527] = bf16(W^T), [n][k] layout.
// ---------------------------------------------------------------------------
__global__ void cvt_w_kernel(const float* __restrict__ W,
                             unsigned short* __restrict__ Wt)
{
    int g = blockIdx.x * blockDim.x + threadIdx.x;
    if (g >= F_IN * HC) return;
    int k = g / HC, n = g % HC;
    Wt[n * F_IN + k] = f2bf(W[g]);
}

// ---------------------------------------------------------------------------
// K0b: Wt rows 528..623 = attention logit weights as GEMM columns.
//  row 528+h   (h<33): Ws[k,h] = sum_c W[k][h*16+c] * att_src[h][c]
//  row 576+h   (h<33): Wd[k,h] = likewise with att_dst; other rows zero.
// a_src = x @ Ws, a_dst = x @ Wd then fall out of the main GEMM — no shfl
// epilogue needed.
// ---------------------------------------------------------------------------
__global__ void att_w_kernel(const float* __restrict__ W,
                             const float* __restrict__ att_src,
                             const float* __restrict__ att_dst,
                             unsigned short* __restrict__ Wt)
{
    int g = blockIdx.x * blockDim.x + threadIdx.x;
    if (g >= 96 * F_IN) return;
    int nl = g >> 7, k = g & 127;      // nl 0..95
    int grp = nl / 48, h = nl % 48;
    float v = 0.f;
    if (h < H_HEADS) {
        const float* att = grp ? att_dst : att_src;
        const float* wr  = W + (size_t)k * HC + h * C_CH;
        #pragma unroll
        for (int c = 0; c < C_CH; ++c) v += wr[c] * att[h * C_CH + c];
    }
    Wt[(size_t)(HC + nl) * F_IN + k] = f2bf(v);
}

// ---------------------------------------------------------------------------
// K1: h = x @ W via MFMA 16x16x32 bf16. One block per 64 rows; f32 x-tile
// staged once (bf16 convert fused), A fragments in registers, 13 groups
// looped internally (Wt is L2-resident). Groups 0..10 -> hb column-blocked
// [j][row][48]; group 11 -> a_src[row][33]; group 12 -> ad2[row][0..32]
// (a_dst half of the interleaved a_dst|denom array).
// No shfl epilogue, no extra LDS: 30.5KB -> 5 blocks/CU.
// ---------------------------------------------------------------------------
#define LDA 136
__global__ __launch_bounds__(256) void gemm_att_kernel(
    const float* __restrict__ x, const unsigned short* __restrict__ Wt,
    unsigned short* __restrict__ hb,
    float* __restrict__ a_src, float* __restrict__ ad2, int N)
{
    __shared__ unsigned short As[64][LDA];   // As[m][k]
    __shared__ unsigned short Bs[48][LDA];   // Bs[n][k] (= Wt rows)

    const int tid  = threadIdx.x;
    const int lane = tid & 63;
    const int wave = tid >> 6;
    const int lm   = lane & 15;
    const int kc   = lane >> 4;
    const int m0   = blockIdx.x * 64;
    const size_t segN = (size_t)N * 48;

    // stage As from f32 x, converting: 64 rows x 32 float4 chunks
    for (int e = tid; e < 64 * 32; e += 256) {
        int r = e >> 5, c = e & 31;
        int gr = m0 + r;
        float4 v = (gr < N) ? ((const float4*)(x + (size_t)gr * F_IN))[c]
                            : make_float4(0.f, 0.f, 0.f, 0.f);
        unsigned int lo = (unsigned int)f2bf(v.x) | ((unsigned int)f2bf(v.y) << 16);
        unsigned int hi = (unsigned int)f2bf(v.z) | ((unsigned int)f2bf(v.w) << 16);
        *(uint2*)&As[r][c * 4] = make_uint2(lo, hi);
    }
    __syncthreads();

    // A fragments live in registers across all 13 group iterations
    const int arow = wave * 16 + lm;
    bf16x8 afrag[4];
    #pragma unroll
    for (int ks = 0; ks < 4; ++ks)
        afrag[ks] = *(const bf16x8*)&As[arow][ks * 32 + kc * 8];

    #pragma unroll 1
    for (int j = 0; j < JGT; ++j) {
        __syncthreads();   // previous iteration's Bs reads done
        for (int e = tid; e < 48 * 16; e += 256) {
            int r = e >> 4, c = e & 15;
            uint4 v = ((const uint4*)(Wt + (size_t)(j * 48 + r) * F_IN))[c];
            *(uint4*)&Bs[r][c * 8] = v;
        }
        __syncthreads();

        floatx4 acc[3] = {};
        #pragma unroll
        for (int ks = 0; ks < 4; ++ks) {
            #pragma unroll
            for (int t = 0; t < 3; ++t) {
                bf16x8 b = *(const bf16x8*)&Bs[t * 16 + lm][ks * 32 + kc * 8];
                acc[t] = __builtin_amdgcn_mfma_f32_16x16x32_bf16(afrag[ks], b, acc[t], 0, 0, 0);
            }
        }

        // C/D layout: col = lane&15, row = (lane>>4)*4 + reg
        #pragma unroll
        for (int t = 0; t < 3; ++t) {
            #pragma unroll
            for (int rr = 0; rr < 4; ++rr) {
                const int row = m0 + wave * 16 + kc * 4 + rr;
                if (row >= N) continue;
                if (j < JG) {
                    hb[(size_t)j * segN + (size_t)row * 48 + t * 16 + lm] =
                        f2bf(acc[t][rr]);
                } else {
                    const int col = t * 16 + lm;
                    if (col < H_HEADS) {
                        if (j == JG) a_src[(size_t)row * H_HEADS + col] = acc[t][rr];
                        else         ad2[(size_t)row * 66 + col]        = acc[t][rr];
                    }
                }
            }
        }
    }
}

// ---------------------------------------------------------------------------
// Counting sort of edges (incl. self loops) by src (for aggregate's h gather
// locality) AND by dst (for atomic-free denom).
// ---------------------------------------------------------------------------
__global__ void hist_kernel(const int* __restrict__ ei,
                            int* __restrict__ hist_s, int* __restrict__ hist_d,
                            int E, int Et)
{
    int g = blockIdx.x * blockDim.x + threadIdx.x;
    if (g >= Et) return;
    int src, dst;
    if (g < E) { src = ei[g]; dst = ei[E + g]; }
    else       { src = dst = g - E; }
    atomicAdd(&hist_s[src], 1);
    atomicAdd(&hist_d[dst], 1);
}

// exclusive scan, 8 elems/thread; grid=2: block0 scans hist_s->cur_s,
// block1 scans hist_d->cur_d+off_d (the two scans run concurrently).
__global__ __launch_bounds__(1024) void scan_kernel(
    const int* __restrict__ hist_s, int* __restrict__ cur_s,
    const int* __restrict__ hist_d, int* __restrict__ cur_d,
    int* __restrict__ off_d, int n)
{
    const int* hist = blockIdx.x ? hist_d : hist_s;
    int* o0 = blockIdx.x ? cur_d : cur_s;
    int* o1 = blockIdx.x ? off_d : (int*)nullptr;

    __shared__ int warp_sums[16];
    __shared__ int s_carry;
    const int tid  = threadIdx.x;
    const int lane = tid & 63, wid = tid >> 6;
    if (tid == 0) s_carry = 0;
    __syncthreads();
    const int n8 = (n + 7) >> 3;
    for (int base = 0; base < n8; base += 1024) {
        int i8 = base + tid;
        int v[8];
        if (i8 * 8 + 8 <= n) {
            *(int4*)&v[0] = ((const int4*)hist)[i8 * 2];
            *(int4*)&v[4] = ((const int4*)hist)[i8 * 2 + 1];
        } else {
            #pragma unroll
            for (int k = 0; k < 8; ++k) v[k] = (i8 * 8 + k < n) ? hist[i8 * 8 + k] : 0;
        }
        int tsum = 0;
        #pragma unroll
        for (int k = 0; k < 8; ++k) tsum += v[k];
        int s = tsum;
        #pragma unroll
        for (int dd = 1; dd < 64; dd <<= 1) {
            int t = __shfl_up(s, dd);
            if (lane >= dd) s += t;
        }
        if (lane == 63) warp_sums[wid] = s;
        __syncthreads();
        if (tid < 16) {
            int ws = warp_sums[tid];
            #pragma unroll
            for (int dd = 1; dd < 16; dd <<= 1) {
                int t = __shfl_up(ws, dd);
                if (tid >= dd) ws += t;
            }
            warp_sums[tid] = ws;
        }
        __syncthreads();
        int excl = s_carry + (wid ? warp_sums[wid - 1] : 0) + (s - tsum);
        int o[8];
        #pragma unroll
        for (int k = 0; k < 8; ++k) { o[k] = excl; excl += v[k]; }
        if (i8 * 8 + 8 <= n) {
            ((int4*)o0)[i8 * 2] = *(int4*)&o[0]; ((int4*)o0)[i8 * 2 + 1] = *(int4*)&o[4];
            if (o1) { ((int4*)o1)[i8 * 2] = *(int4*)&o[0]; ((int4*)o1)[i8 * 2 + 1] = *(int4*)&o[4]; }
        } else {
            for (int k = 0; k < 8; ++k)
                if (i8 * 8 + k < n) {
                    o0[i8 * 8 + k] = o[k];
                    if (o1) o1[i8 * 8 + k] = o[k];
                }
        }
        __syncthreads();
        if (tid == 0) s_carry = s_carry + warp_sums[15];
        __syncthreads();
    }
}

__global__ void scatter_kernel(const int* __restrict__ ei,
                               int* __restrict__ cur_s, int* __restrict__ cur_d,
                               int* __restrict__ es, int* __restrict__ ed,
                               int* __restrict__ ss2, int E, int Et)
{
    int g = blockIdx.x * blockDim.x + threadIdx.x;
    if (g >= Et) return;
    int src, dst;
    if (g < E) { src = ei[g]; dst = ei[E + g]; }
    else       { src = dst = g - E; }
    int ps = atomicAdd(&cur_s[src], 1);
    es[ps] = src;
    ed[ps] = dst;
    int pd = atomicAdd(&cur_d[dst], 1);
    ss2[pd] = src;
}

// ---------------------------------------------------------------------------
// K2: denom, atomic-free. One wave per destination node: its incoming edges
// are a contiguous run in dst-sorted ss2. Lanes 0..32 = heads. Result goes
// to ad2[d][33..65] (interleaved with a_dst so aggregate's random per-dst
// gather touches one 264B region instead of two distant 132B rows).
// ---------------------------------------------------------------------------
__global__ __launch_bounds__(256) void denom_kernel(
    const int* __restrict__ off_d, const int* __restrict__ ss2,
    const float* __restrict__ a_src, float* __restrict__ ad2, int N, int Et)
{
    const int d = blockIdx.x * 4 + (threadIdx.x >> 6);
    if (d >= N) return;
    const int lane = threadIdx.x & 63;
    const int beg = off_d[d];
    const int end = (d + 1 < N) ? off_d[d + 1] : Et;
    const float ad = (lane < H_HEADS) ? ad2[(size_t)d * 66 + lane] : 0.f;
    float acc = 0.f;
    int src = ss2[beg];
    for (int e = beg; e < end; ++e) {
        int nxt = (e + 1 < end) ? ss2[e + 1] : 0;
        float v = (lane < H_HEADS) ? (a_src[src * H_HEADS + lane] + ad) : 0.f;
        v = v > 0.f ? v : NEG_SLOPE * v;
        acc += __expf(v);
        src = nxt;
    }
    if (lane < H_HEADS) ad2[(size_t)d * 66 + 33 + lane] = acc;
}

// ---------------------------------------------------------------------------
// K3: 64 src-sorted edges/block. Phase 1: 64x33 alphas into LDS (inv folded).
// Phase 2: lane (edge,c) gathers bf16 h from the 11 column-block segments
// (same src repeats across consecutive edges -> cache hits), one atomic per
// (edge,c). Bijective XCD-chunk swizzle keeps a src run on one XCD's L2.
// ---------------------------------------------------------------------------
#define EPB 64
__global__ __launch_bounds__(256) void aggregate_kernel(
    const int* __restrict__ es, const int* __restrict__ ed,
    const float* __restrict__ a_src, const float* __restrict__ ad2,
    const unsigned short* __restrict__ hb,
    float* __restrict__ out, int N, int Et)
{
    __shared__ int   s_src[EPB], s_dst[EPB];
    __shared__ float s_alpha[EPB][H_HEADS];

    // bijective XCD-chunked block swizzle (m204 formula)
    const int nwg = gridDim.x;
    const int q = nwg >> 3, r = nwg & 7;
    const int xcd = blockIdx.x & 7, idx = blockIdx.x >> 3;
    const int bid = (xcd < r ? xcd * (q + 1) : r * (q + 1) + (xcd - r) * q) + idx;

    const int tid = threadIdx.x;
    const int e0  = bid * EPB;
    const size_t segN = (size_t)N * 48;

    if (tid < EPB * 2) {
        int el = tid & (EPB - 1);
        int e  = e0 + el;
        int v  = 0;
        if (e < Et) v = (tid < EPB) ? es[e] : ed[e];
        if (tid < EPB) s_src[el] = v; else s_dst[el] = v;
    }
    __syncthreads();

    for (int i = tid; i < EPB * H_HEADS; i += 256) {
        int el = i / H_HEADS, hd = i - el * H_HEADS;
        if (e0 + el < Et) {
            int src = s_src[el], dst = s_dst[el];
            float v = a_src[src * H_HEADS + hd] + ad2[(size_t)dst * 66 + hd];
            v = v > 0.f ? v : NEG_SLOPE * v;
            s_alpha[el][hd] = __expf(v) / (ad2[(size_t)dst * 66 + 33 + hd] + 1e-16f);
        }
    }
    __syncthreads();

    const int elq = tid >> 4, c = tid & 15;
    for (int el = elq; el < EPB; el += 16) {
        int e = e0 + el;
        if (e >= Et) break;
        int src = s_src[el], dst = s_dst[el];
        const unsigned short* hp = hb + (size_t)src * 48 + c;
        float acc = 0.f;
        #pragma unroll
        for (int j = 0; j < JG; ++j) {
            const unsigned short* pj = hp + (size_t)j * segN;
            acc += s_alpha[el][j * 3 + 0] * bf2f(pj[0]);
            acc += s_alpha[el][j * 3 + 1] * bf2f(pj[16]);
            acc += s_alpha[el][j * 3 + 2] * bf2f(pj[32]);
        }
        atomicAdd(&out[dst * C_CH + c], acc);
    }
}

// K4: out = tanh(out/H + bias), in place
__global__ void finalize_kernel(float* __restrict__ out,
                                const float* __restrict__ bias, int total)
{
    int g = blockIdx.x * blockDim.x + threadIdx.x;
    if (g >= total) return;
    out[g] = tanhf(out[g] * (1.0f / 33.0f) + bias[g & 15]);
}

// ---------------------------------------------------------------------------
extern "C" void kernel_launch(void* const* d_in, const int* in_sizes, int n_in,
                              void* d_out, int out_size, void* d_ws, size_t ws_size,
                              hipStream_t stream)
{
    const float* x       = (const float*)d_in[0];
    const int*   ei      = (const int*)  d_in[1];
    const float* W       = (const float*)d_in[2];
    const float* att_src = (const float*)d_in[3];
    const float* att_dst = (const float*)d_in[4];
    const float* bias    = (const float*)d_in[5];
    float* out = (float*)d_out;

    const int N  = in_sizes[0] / F_IN;   // 50000
    const int E  = in_sizes[1] / 2;      // 320000
    const int Et = E + N;                // with self loops

    // workspace layout (all 16B-aligned for these sizes)
    unsigned short* hb = (unsigned short*)d_ws;          // 11 segments [N][48]
    float* a_src  = (float*)(hb + (size_t)N * HC);       // [N][33]
    float* ad2    = a_src + (size_t)N * H_HEADS;         // [N][66] a_dst|denom
    int*   es     = (int*)(ad2 + (size_t)N * 66);
    int*   ed     = es + Et;
    int*   ss2    = ed + Et;
    int*   hist_s = ss2 + Et;
    int*   hist_d = hist_s + N;
    int*   cur_s  = hist_d + N;
    int*   cur_d  = cur_s + N;
    int*   off_d  = cur_d + N;
    unsigned short* Wt = (unsigned short*)(off_d + N);   // [624][128]

    hipMemsetAsync(d_out, 0, (size_t)out_size * sizeof(float), stream);
    hipMemsetAsync(hist_s, 0, 2 * (size_t)N * sizeof(int), stream);  // hist_s + hist_d

    cvt_w_kernel<<<(F_IN * HC + 255) / 256, 256, 0, stream>>>(W, Wt);
    att_w_kernel<<<(96 * F_IN + 255) / 256, 256, 0, stream>>>(W, att_src, att_dst, Wt);

    gemm_att_kernel<<<(N + 63) / 64, 256, 0, stream>>>(x, Wt, hb, a_src, ad2, N);

    hist_kernel<<<(Et + 255) / 256, 256, 0, stream>>>(ei, hist_s, hist_d, E, Et);
    scan_kernel<<<2, 1024, 0, stream>>>(hist_s, cur_s, hist_d, cur_d, off_d, N);
    scatter_kernel<<<(Et + 255) / 256, 256, 0, stream>>>(ei, cur_s, cur_d,
                                                         es, ed, ss2, E, Et);

    denom_kernel<<<(N + 3) / 4, 256, 0, stream>>>(off_d, ss2, a_src, ad2, N, Et);

    aggregate_kernel<<<(Et + EPB - 1) / EPB, 256, 0, stream>>>(
        es, ed, a_src, ad2, hb, out, N, Et);

    int totO = N * C_CH;
    finalize_kernel<<<(totO + 255) / 256, 256, 0, stream>>>(out, bias, totO);
}